// Round 6
// baseline (143.115 us; speedup 1.0000x reference)
//
#include <hip/hip_runtime.h>
#include <stdint.h>

#define HH 128
#define WW 128
#define NTILES 16
#define NPIX (HH * WW)        // 16384 = NTILES*1024 tile-space pixels
#define MAXSEG 16
#define JCH 1024              // j-chunk per k1 block

// ---------------------------------------------------------------------------
// k0: init — zero rank, build stable sort keys.
// key[i] = (bits(depth_i) << 32) | i.  depths > 0, so IEEE bit pattern order
// == float order; low bits give the stable (index) tie-break. Then
// (d_j < d_i) || (d_j == d_i && j < i)  <=>  key_j < key_i.
// ---------------------------------------------------------------------------
__global__ void k0_init(const float* __restrict__ depths,
                        uint64_t* __restrict__ keys,
                        int* __restrict__ rank, int N) {
    int i = blockIdx.x * blockDim.x + threadIdx.x;
    if (i < N) {
        rank[i] = 0;
        keys[i] = ((uint64_t)__float_as_uint(depths[i]) << 32) | (uint64_t)i;
    }
}

// ---------------------------------------------------------------------------
// k1: rank by counting, u64 keys. j-side reads are block-uniform -> compiler
// scalarizes to s_load (scalar pipe, K$); vector pipe does cmp+add only.
// ---------------------------------------------------------------------------
__global__ __launch_bounds__(256) void k1_rank(const uint64_t* __restrict__ keys,
                                               int* __restrict__ rank,
                                               int N, int ncj) {
    int bi = blockIdx.x / ncj;
    int bj = blockIdx.x % ncj;
    int t  = threadIdx.x;
    int i  = bi * 256 + t;
    uint64_t ki = (i < N) ? keys[i] : 0;

    int j0   = bj * JCH;
    int jend = min(N, j0 + JCH);

    int c0 = 0, c1 = 0, c2 = 0, c3 = 0;
    int j = j0;
    for (; j + 4 <= jend; j += 4) {
        uint64_t a = keys[j + 0];
        uint64_t b = keys[j + 1];
        uint64_t c = keys[j + 2];
        uint64_t d = keys[j + 3];
        c0 += (a < ki);
        c1 += (b < ki);
        c2 += (c < ki);
        c3 += (d < ki);
    }
    for (; j < jend; j++) c0 += (keys[j] < ki);

    if (i < N) {
        int cnt = (c0 + c1) + (c2 + c3);
        if (cnt) atomicAdd(&rank[i], cnt);
    }
}

// ---------------------------------------------------------------------------
// k2: preprocess gaussian i, scatter 12-float struct to sorted[rank[i]],
// write 16-bit tile-intersection mask to smask[rank[i]].
// struct: [mx, my, A, B, C, opa, cr, cg, cb, depth, pad, pad]
//   gw = exp(-0.5*(A*dx^2 + B*dy^2 + C*dx*dy)), A=c11/det B=c00/det
//   C=-(c01+c10)/det
// ---------------------------------------------------------------------------
__global__ __launch_bounds__(256) void k2_scatter(const float* __restrict__ means,
                                                  const float* __restrict__ cov,
                                                  const float* __restrict__ color,
                                                  const float* __restrict__ opac,
                                                  const float* __restrict__ depths,
                                                  const int* __restrict__ rank,
                                                  float* __restrict__ sorted,
                                                  int* __restrict__ smask,
                                                  int N) {
    int i = blockIdx.x * blockDim.x + threadIdx.x;
    if (i >= N) return;

    float mx = means[2 * i + 0];
    float my = means[2 * i + 1];
    float c00 = cov[4 * i + 0];
    float c01 = cov[4 * i + 1];
    float c10 = cov[4 * i + 2];
    float c11 = cov[4 * i + 3];

    float det = c00 * c11 - c01 * c10;
    float mid = 0.5f * (c00 + c11);
    float s = sqrtf(fmaxf(mid * mid - det, 0.1f));
    float radii = 3.0f * ceilf(sqrtf(fmaxf(mid + s, mid - s)));

    float rminx = fminf(fmaxf(mx - radii, 0.0f), (float)(WW - 1));
    float rminy = fminf(fmaxf(my - radii, 0.0f), (float)(HH - 1));
    float rmaxx = fminf(fmaxf(mx + radii, 0.0f), (float)(WW - 1));
    float rmaxy = fminf(fmaxf(my + radii, 0.0f), (float)(HH - 1));

    float inv_det = 1.0f / det;
    float A = c11 * inv_det;
    float B = c00 * inv_det;
    float C = -(c01 + c10) * inv_det;

    int bits = 0;
    for (int ty = 0; ty < 4; ty++) {
        float h = (float)(ty * 32);
        float tly = fmaxf(rminy, h);
        float bry = fminf(rmaxy, h + 31.0f);
        bool yok = bry > tly;
        for (int tx = 0; tx < 4; tx++) {
            float w = (float)(tx * 32);
            float tlx = fmaxf(rminx, w);
            float brx = fminf(rmaxx, w + 31.0f);
            if (yok && (brx > tlx)) bits |= 1 << (ty * 4 + tx);
        }
    }

    int r = rank[i];
    float4* g4 = (float4*)(sorted + (size_t)r * 12);
    g4[0] = make_float4(mx, my, A, B);
    g4[1] = make_float4(C, opac[i], color[3 * i + 0], color[3 * i + 1]);
    g4[2] = make_float4(color[3 * i + 2], depths[i], 0.0f, 0.0f);
    smask[r] = bits;
}

// ---------------------------------------------------------------------------
// k3: per-tile order-preserving compaction of sorted indices.
// One block (256 threads) per tile; ballot+popcount scan.
// ---------------------------------------------------------------------------
__global__ __launch_bounds__(256) void k3_compact(const int* __restrict__ smask,
                                                  int* __restrict__ lists,
                                                  int* __restrict__ counts,
                                                  int N) {
    int tile = blockIdx.x;
    int t = threadIdx.x;
    int lane = t & 63;
    int wv = t >> 6;

    __shared__ int wsum[4];
    __shared__ int s_run;
    if (t == 0) s_run = 0;
    __syncthreads();

    int* list = lists + (size_t)tile * N;

    for (int base = 0; base < N; base += 256) {
        int idx = base + t;
        int flag = (idx < N) ? ((smask[idx] >> tile) & 1) : 0;
        unsigned long long bal = __ballot(flag);
        int pre = __popcll(bal & ((lane == 0) ? 0ull : ((1ull << lane) - 1ull)));
        int wtot = __popcll(bal);
        if (lane == 0) wsum[wv] = wtot;
        __syncthreads();
        int woff = 0;
        for (int q = 0; q < wv; q++) woff += wsum[q];
        int run = s_run;
        if (flag) list[run + woff + pre] = idx;
        __syncthreads();
        if (t == 0) s_run = run + wsum[0] + wsum[1] + wsum[2] + wsum[3];
        __syncthreads();
    }
    if (t == 0) counts[tile] = s_run;
}

// ---------------------------------------------------------------------------
// k4: segmented render. Grid = 64*S blocks: (tile, pixel-quarter, segment).
// Front-to-back compositing is associative under
// merge(P,Q) = (P.acc + P.T*Q.acc, P.T*Q.T) -> segments combine in k5.
// partials: part4[s*NPIX+pid] = (r,g,b,d), part2[s*NPIX+pid] = (a,T)
// ---------------------------------------------------------------------------
#define CH 64
__global__ __launch_bounds__(256) void k4_render(const float* __restrict__ sorted,
                                                 const int* __restrict__ lists,
                                                 const int* __restrict__ counts,
                                                 float4* __restrict__ part4,
                                                 float2* __restrict__ part2,
                                                 int N, int S) {
    int b = blockIdx.x;            // 0 .. 64*S-1
    int s = b & (S - 1);           // segment (S is a power of two)
    int q = b / S;                 // 0..63
    int tile = q >> 2;
    int sub = q & 3;
    int tx = tile & 3;
    int ty = tile >> 2;
    int t = threadIdx.x;

    int p = sub * 256 + t;         // pixel index within tile, 0..1023
    int px = p & 31;
    int py = p >> 5;
    float fx = (float)(tx * 32 + px);
    float fy = (float)(ty * 32 + py);

    int cnt = counts[tile];
    int chunk = (cnt + S - 1) / S;
    int beg = s * chunk;
    int end = min(cnt, beg + chunk);
    const int* list = lists + (size_t)tile * N;

    __shared__ __align__(16) float4 s_g[CH * 3];
    __shared__ int s_idx[CH];

    float T = 1.0f;
    float ar = 0.0f, ag = 0.0f, ab = 0.0f, ad = 0.0f, aa = 0.0f;

    for (int base = beg; base < end; base += CH) {
        int m = min(CH, end - base);
        if (t < CH) s_idx[t] = (t < m) ? list[base + t] : 0;
        __syncthreads();
        // one pass: m*3 <= 192 float4 gathers, 16B/lane coalesced
        if (t < m * 3) {
            int k = t / 3;
            int c = t - k * 3;
            s_g[t] = ((const float4*)(sorted + (size_t)s_idx[k] * 12))[c];
        }
        __syncthreads();
        for (int k = 0; k < m; k++) {
            float4 ga = s_g[k * 3 + 0];   // mx, my, A, B
            float4 gb = s_g[k * 3 + 1];   // C, opa, cr, cg
            float4 gc = s_g[k * 3 + 2];   // cb, depth, -, -
            float dx = fx - ga.x;
            float dy = fy - ga.y;
            float e = ga.z * dx * dx + ga.w * dy * dy + gb.x * dx * dy;
            float gw = __expf(-0.5f * e);
            float alpha = fminf(gw * gb.y, 0.99f);
            float w = T * alpha;
            ar += w * gb.z;
            ag += w * gb.w;
            ab += w * gc.x;
            ad += w * gc.y;
            aa += w;
            T *= (1.0f - alpha);
        }
        __syncthreads();
    }

    size_t o = (size_t)s * NPIX + (size_t)tile * 1024 + p;
    part4[o] = make_float4(ar, ag, ab, ad);
    part2[o] = make_float2(aa, T);
}

// ---------------------------------------------------------------------------
// k5: combine the S depth-segments per pixel (in order) and add background.
// ---------------------------------------------------------------------------
__global__ __launch_bounds__(256) void k5_combine(const float4* __restrict__ part4,
                                                  const float2* __restrict__ part2,
                                                  float* __restrict__ out, int S) {
    int pid = blockIdx.x * 256 + threadIdx.x;   // tile-space pixel id
    int tile = pid >> 10;
    int p = pid & 1023;
    int px = p & 31;
    int py = p >> 5;
    int gx = (tile & 3) * 32 + px;
    int gy = (tile >> 2) * 32 + py;

    float T = 1.0f;
    float ar = 0.0f, ag = 0.0f, ab = 0.0f, ad = 0.0f, aa = 0.0f;
    for (int s = 0; s < S; s++) {
        float4 q4 = part4[(size_t)s * NPIX + pid];
        float2 q2 = part2[(size_t)s * NPIX + pid];
        ar += T * q4.x;
        ag += T * q4.y;
        ab += T * q4.z;
        ad += T * q4.w;
        aa += T * q2.x;
        T *= q2.y;
    }

    int pidx = gy * WW + gx;
    float bgr = 1.0f - aa;
    out[pidx * 3 + 0] = ar + bgr;
    out[pidx * 3 + 1] = ag + bgr;
    out[pidx * 3 + 2] = ab + bgr;
    out[HH * WW * 3 + pidx] = ad;
    out[HH * WW * 4 + pidx] = aa;
}

// ---------------------------------------------------------------------------
extern "C" void kernel_launch(void* const* d_in, const int* in_sizes, int n_in,
                              void* d_out, int out_size, void* d_ws, size_t ws_size,
                              hipStream_t stream) {
    const float* means  = (const float*)d_in[0];
    const float* cov    = (const float*)d_in[1];
    const float* color  = (const float*)d_in[2];
    const float* opac   = (const float*)d_in[3];
    const float* depths = (const float*)d_in[4];
    float* out = (float*)d_out;

    int N = in_sizes[4];
    size_t NA = ((size_t)N + 255) / 256 * 256;   // padded N for alignment

    // workspace layout (sections 256B-aligned)
    size_t o_rank   = 0;                         // N ints
    size_t o_keys   = o_rank + NA * 4;           // N u64
    size_t o_sorted = o_keys + NA * 8;           // N * 12 floats
    size_t o_smask  = o_sorted + NA * 48;        // N ints
    size_t o_lists  = o_smask + NA * 4;          // 16 * N ints
    size_t o_counts = o_lists + (size_t)NTILES * NA * 4; // 16 ints
    size_t o_part4  = o_counts + 256;            // S * NPIX float4
    // part2 sits directly after part4 (sized by the ACTUAL S):
    //   footprint(S) = o_part4 + S*NPIX*16 + S*NPIX*8

    // largest power-of-two S <= MAXSEG whose COMPLETE footprint fits
    // (ws_size is constant per call -> stable grid for graph capture)
    int S = 1;
    while (S < MAXSEG &&
           o_part4 + (size_t)(S * 2) * NPIX * 24 <= ws_size) S *= 2;
    size_t o_part2 = o_part4 + (size_t)S * NPIX * 16;

    int*      rank     = (int*)((char*)d_ws + o_rank);
    uint64_t* keys     = (uint64_t*)((char*)d_ws + o_keys);
    float*    sorted   = (float*)((char*)d_ws + o_sorted);
    int*      smask    = (int*)((char*)d_ws + o_smask);
    int*      lists    = (int*)((char*)d_ws + o_lists);
    int*      counts   = (int*)((char*)d_ws + o_counts);
    float4*   part4    = (float4*)((char*)d_ws + o_part4);
    float2*   part2    = (float2*)((char*)d_ws + o_part2);

    int nb  = (N + 255) / 256;
    int ncj = (N + JCH - 1) / JCH;

    k0_init<<<nb, 256, 0, stream>>>(depths, keys, rank, N);
    k1_rank<<<nb * ncj, 256, 0, stream>>>(keys, rank, N, ncj);
    k2_scatter<<<nb, 256, 0, stream>>>(means, cov, color, opac, depths, rank,
                                       sorted, smask, N);
    k3_compact<<<NTILES, 256, 0, stream>>>(smask, lists, counts, N);
    k4_render<<<64 * S, 256, 0, stream>>>(sorted, lists, counts, part4, part2,
                                          N, S);
    k5_combine<<<NPIX / 256, 256, 0, stream>>>(part4, part2, out, S);
}

// Round 8
// 140.146 us; speedup vs baseline: 1.0212x; 1.0212x over previous
//
#include <hip/hip_runtime.h>
#include <stdint.h>

#define HH 128
#define WW 128
#define NTILES 16
#define NPIX (HH * WW)        // 16384 = NTILES*1024 tile-space pixels
#define MAXSEG 16
#define JCH 512               // j-chunk per k1 block

// ---------------------------------------------------------------------------
// Stable sort key: key[i] = (bits(depth_i) << 32) | i. depths > 0, so IEEE
// bit order == float order; low 32 bits give the stable index tie-break.
// (d_j < d_i) || (d_j == d_i && j < i)  <=>  key_j < key_i.
// ---------------------------------------------------------------------------
__device__ __forceinline__ uint64_t mkkey(float d, int i) {
    return ((uint64_t)__float_as_uint(d) << 32) | (uint64_t)(uint32_t)i;
}

// ---------------------------------------------------------------------------
// k1: rank partial counts. Block (bi,bj): lanes hold i-keys; loop over the
// bj-th j-chunk with block-uniform depth loads (scalarized to s_load; key
// built on the scalar pipe). No atomics, no init: part[bj*NA + i] = cnt.
// ---------------------------------------------------------------------------
__global__ __launch_bounds__(256) void k1_rank(const float* __restrict__ depths,
                                               int* __restrict__ part,
                                               int N, int ncj, int NA) {
    int bi = blockIdx.x / ncj;
    int bj = blockIdx.x % ncj;
    int t  = threadIdx.x;
    int i  = bi * 256 + t;
    float di = (i < N) ? depths[i] : 0.0f;
    uint64_t ki = mkkey(di, i);

    int j0   = bj * JCH;
    int jend = min(N, j0 + JCH);

    int c0 = 0, c1 = 0, c2 = 0, c3 = 0;
    int j = j0;
    for (; j + 4 <= jend; j += 4) {
        uint64_t a = mkkey(depths[j + 0], j + 0);
        uint64_t b = mkkey(depths[j + 1], j + 1);
        uint64_t c = mkkey(depths[j + 2], j + 2);
        uint64_t d = mkkey(depths[j + 3], j + 3);
        c0 += (a < ki);
        c1 += (b < ki);
        c2 += (c < ki);
        c3 += (d < ki);
    }
    for (; j < jend; j++) c0 += (mkkey(depths[j], j) < ki);

    if (i < N) part[(size_t)bj * NA + i] = (c0 + c1) + (c2 + c3);
}

// ---------------------------------------------------------------------------
// k2: rank[i] = sum of partials; preprocess gaussian i; scatter 12-float
// struct to sorted[rank[i]]; write 16-bit tile mask to smask[rank[i]].
// struct: [mx, my, A, B, C, opa, cr, cg, cb, depth, pad, pad]
//   gw = exp(-0.5*(A*dx^2 + B*dy^2 + C*dx*dy)), A=c11/det B=c00/det
//   C=-(c01+c10)/det
// ---------------------------------------------------------------------------
__global__ __launch_bounds__(256) void k2_scatter(const float* __restrict__ means,
                                                  const float* __restrict__ cov,
                                                  const float* __restrict__ color,
                                                  const float* __restrict__ opac,
                                                  const float* __restrict__ depths,
                                                  const int* __restrict__ part,
                                                  float* __restrict__ sorted,
                                                  int* __restrict__ smask,
                                                  int N, int ncj, int NA) {
    int i = blockIdx.x * blockDim.x + threadIdx.x;
    if (i >= N) return;

    int r = 0;
    for (int b = 0; b < ncj; b++) r += part[(size_t)b * NA + i];

    float mx = means[2 * i + 0];
    float my = means[2 * i + 1];
    float c00 = cov[4 * i + 0];
    float c01 = cov[4 * i + 1];
    float c10 = cov[4 * i + 2];
    float c11 = cov[4 * i + 3];

    float det = c00 * c11 - c01 * c10;
    float mid = 0.5f * (c00 + c11);
    float s = sqrtf(fmaxf(mid * mid - det, 0.1f));
    float radii = 3.0f * ceilf(sqrtf(fmaxf(mid + s, mid - s)));

    float rminx = fminf(fmaxf(mx - radii, 0.0f), (float)(WW - 1));
    float rminy = fminf(fmaxf(my - radii, 0.0f), (float)(HH - 1));
    float rmaxx = fminf(fmaxf(mx + radii, 0.0f), (float)(WW - 1));
    float rmaxy = fminf(fmaxf(my + radii, 0.0f), (float)(HH - 1));

    float inv_det = 1.0f / det;
    float A = c11 * inv_det;
    float B = c00 * inv_det;
    float C = -(c01 + c10) * inv_det;

    int bits = 0;
    for (int ty = 0; ty < 4; ty++) {
        float h = (float)(ty * 32);
        float tly = fmaxf(rminy, h);
        float bry = fminf(rmaxy, h + 31.0f);
        bool yok = bry > tly;
        for (int tx = 0; tx < 4; tx++) {
            float w = (float)(tx * 32);
            float tlx = fmaxf(rminx, w);
            float brx = fminf(rmaxx, w + 31.0f);
            if (yok && (brx > tlx)) bits |= 1 << (ty * 4 + tx);
        }
    }

    float4* g4 = (float4*)(sorted + (size_t)r * 12);
    g4[0] = make_float4(mx, my, A, B);
    g4[1] = make_float4(C, opac[i], color[3 * i + 0], color[3 * i + 1]);
    g4[2] = make_float4(color[3 * i + 2], depths[i], 0.0f, 0.0f);
    smask[r] = bits;
}

// ---------------------------------------------------------------------------
// k3: per-tile order-preserving compaction of sorted indices.
// One block (1024 threads = 16 waves) per tile; ballot+popcount scan.
// ---------------------------------------------------------------------------
__global__ __launch_bounds__(1024) void k3_compact(const int* __restrict__ smask,
                                                   int* __restrict__ lists,
                                                   int* __restrict__ counts,
                                                   int N) {
    int tile = blockIdx.x;
    int t = threadIdx.x;
    int lane = t & 63;
    int wv = t >> 6;            // 0..15

    __shared__ int wsum[16];
    __shared__ int woff[16];
    __shared__ int s_run;
    if (t == 0) s_run = 0;
    __syncthreads();

    int* list = lists + (size_t)tile * N;

    for (int base = 0; base < N; base += 1024) {
        int idx = base + t;
        int flag = (idx < N) ? ((smask[idx] >> tile) & 1) : 0;
        unsigned long long bal = __ballot(flag);
        int pre = __popcll(bal & ((1ull << lane) - 1ull));
        if (lane == 63) wsum[wv] = pre + flag;
        __syncthreads();
        if (wv == 0 && lane < 16) {
            int v = 0;
            for (int q = 0; q < lane; q++) v += wsum[q];
            woff[lane] = v;
        }
        __syncthreads();
        int run = s_run;
        if (flag) list[run + woff[wv] + pre] = idx;
        __syncthreads();
        if (t == 0) s_run = run + woff[15] + wsum[15];
        __syncthreads();
    }
    if (t == 0) counts[tile] = s_run;
}

// ---------------------------------------------------------------------------
// k4: segmented render. Grid = 64*S blocks: (tile, pixel-quarter, segment).
// Front-to-back compositing is associative under
// merge(P,Q) = (P.acc + P.T*Q.acc, P.T*Q.T) -> segments combine in k5.
// partials: part4[s*NPIX+pid] = (r,g,b,d), part2[s*NPIX+pid] = (a,T)
// ---------------------------------------------------------------------------
#define CH 64
__global__ __launch_bounds__(256) void k4_render(const float* __restrict__ sorted,
                                                 const int* __restrict__ lists,
                                                 const int* __restrict__ counts,
                                                 float4* __restrict__ part4,
                                                 float2* __restrict__ part2,
                                                 int N, int S) {
    int b = blockIdx.x;            // 0 .. 64*S-1
    int s = b & (S - 1);           // segment (S is a power of two)
    int q = b / S;                 // 0..63
    int tile = q >> 2;
    int sub = q & 3;
    int tx = tile & 3;
    int ty = tile >> 2;
    int t = threadIdx.x;

    int p = sub * 256 + t;         // pixel index within tile, 0..1023
    int px = p & 31;
    int py = p >> 5;
    float fx = (float)(tx * 32 + px);
    float fy = (float)(ty * 32 + py);

    int cnt = counts[tile];
    int chunk = (cnt + S - 1) / S;
    int beg = s * chunk;
    int end = min(cnt, beg + chunk);
    const int* list = lists + (size_t)tile * N;

    __shared__ __align__(16) float4 s_g[CH * 3];
    __shared__ int s_idx[CH];

    float T = 1.0f;
    float ar = 0.0f, ag = 0.0f, ab = 0.0f, ad = 0.0f, aa = 0.0f;

    for (int base = beg; base < end; base += CH) {
        int m = min(CH, end - base);
        if (t < CH) s_idx[t] = (t < m) ? list[base + t] : 0;
        __syncthreads();
        // one pass: m*3 <= 192 float4 gathers, 16B/lane coalesced
        if (t < m * 3) {
            int k = t / 3;
            int c = t - k * 3;
            s_g[t] = ((const float4*)(sorted + (size_t)s_idx[k] * 12))[c];
        }
        __syncthreads();
        for (int k = 0; k < m; k++) {
            float4 ga = s_g[k * 3 + 0];   // mx, my, A, B
            float4 gb = s_g[k * 3 + 1];   // C, opa, cr, cg
            float4 gc = s_g[k * 3 + 2];   // cb, depth, -, -
            float dx = fx - ga.x;
            float dy = fy - ga.y;
            float e = ga.z * dx * dx + ga.w * dy * dy + gb.x * dx * dy;
            float gw = __expf(-0.5f * e);
            float alpha = fminf(gw * gb.y, 0.99f);
            float w = T * alpha;
            ar += w * gb.z;
            ag += w * gb.w;
            ab += w * gc.x;
            ad += w * gc.y;
            aa += w;
            T *= (1.0f - alpha);
        }
        __syncthreads();
    }

    size_t o = (size_t)s * NPIX + (size_t)tile * 1024 + p;
    part4[o] = make_float4(ar, ag, ab, ad);
    part2[o] = make_float2(aa, T);
}

// ---------------------------------------------------------------------------
// k5: combine the S depth-segments per pixel (in order) and add background.
// ---------------------------------------------------------------------------
__global__ __launch_bounds__(256) void k5_combine(const float4* __restrict__ part4,
                                                  const float2* __restrict__ part2,
                                                  float* __restrict__ out, int S) {
    int pid = blockIdx.x * 256 + threadIdx.x;   // tile-space pixel id
    int tile = pid >> 10;
    int p = pid & 1023;
    int px = p & 31;
    int py = p >> 5;
    int gx = (tile & 3) * 32 + px;
    int gy = (tile >> 2) * 32 + py;

    float T = 1.0f;
    float ar = 0.0f, ag = 0.0f, ab = 0.0f, ad = 0.0f, aa = 0.0f;
    for (int s = 0; s < S; s++) {
        float4 q4 = part4[(size_t)s * NPIX + pid];
        float2 q2 = part2[(size_t)s * NPIX + pid];
        ar += T * q4.x;
        ag += T * q4.y;
        ab += T * q4.z;
        ad += T * q4.w;
        aa += T * q2.x;
        T *= q2.y;
    }

    int pidx = gy * WW + gx;
    float bgr = 1.0f - aa;
    out[pidx * 3 + 0] = ar + bgr;
    out[pidx * 3 + 1] = ag + bgr;
    out[pidx * 3 + 2] = ab + bgr;
    out[HH * WW * 3 + pidx] = ad;
    out[HH * WW * 4 + pidx] = aa;
}

// ---------------------------------------------------------------------------
extern "C" void kernel_launch(void* const* d_in, const int* in_sizes, int n_in,
                              void* d_out, int out_size, void* d_ws, size_t ws_size,
                              hipStream_t stream) {
    const float* means  = (const float*)d_in[0];
    const float* cov    = (const float*)d_in[1];
    const float* color  = (const float*)d_in[2];
    const float* opac   = (const float*)d_in[3];
    const float* depths = (const float*)d_in[4];
    float* out = (float*)d_out;

    int N = in_sizes[4];
    int NA = (int)(((size_t)N + 255) / 256 * 256);   // padded N
    int nb  = (N + 255) / 256;
    int ncj = (N + JCH - 1) / JCH;

    // workspace layout (sections 256B-aligned)
    size_t o_part   = 0;                              // ncj * NA ints (rank partials)
    size_t o_sorted = o_part + (size_t)ncj * NA * 4;  // N * 12 floats
    size_t o_smask  = o_sorted + (size_t)NA * 48;     // N ints
    size_t o_lists  = o_smask + (size_t)NA * 4;       // 16 * N ints
    size_t o_counts = o_lists + (size_t)NTILES * NA * 4; // 16 ints
    size_t o_part4  = o_counts + 256;                 // S * NPIX float4
    // part2 directly after part4 (sized by the ACTUAL S):
    //   footprint(S) = o_part4 + S*NPIX*16 + S*NPIX*8

    // largest power-of-two S <= MAXSEG whose COMPLETE footprint fits
    // (ws_size constant per call -> stable grid for graph capture)
    int S = 1;
    while (S < MAXSEG &&
           o_part4 + (size_t)(S * 2) * NPIX * 24 <= ws_size) S *= 2;
    size_t o_part2 = o_part4 + (size_t)S * NPIX * 16;

    int*    part   = (int*)((char*)d_ws + o_part);
    float*  sorted = (float*)((char*)d_ws + o_sorted);
    int*    smask  = (int*)((char*)d_ws + o_smask);
    int*    lists  = (int*)((char*)d_ws + o_lists);
    int*    counts = (int*)((char*)d_ws + o_counts);
    float4* part4  = (float4*)((char*)d_ws + o_part4);
    float2* part2  = (float2*)((char*)d_ws + o_part2);

    k1_rank<<<nb * ncj, 256, 0, stream>>>(depths, part, N, ncj, NA);
    k2_scatter<<<nb, 256, 0, stream>>>(means, cov, color, opac, depths, part,
                                       sorted, smask, N, ncj, NA);
    k3_compact<<<NTILES, 1024, 0, stream>>>(smask, lists, counts, N);
    k4_render<<<64 * S, 256, 0, stream>>>(sorted, lists, counts, part4, part2,
                                          N, S);
    k5_combine<<<NPIX / 256, 256, 0, stream>>>(part4, part2, out, S);
}